// Round 2
// baseline (1501.386 us; speedup 1.0000x reference)
//
#include <hip/hip_runtime.h>
#include <hip/hip_bf16.h>

// ConstitutiveModel via MFMA: B=2048 samples, T=64 sequential steps, H=128.
// One wave per 16 samples (M-dim of mfma_f32_16x16x32_f16), 128 blocks x 64 thr,
// no barriers (single wave per block). All layers: C[unit][sample] =
// mfma(A=weight-tile, B=act-frag), acts kept in A-frag form (identity
// B-frag(X^T) == A-frag(X)). fp32 accuracy via f16 hi + f16 lo*2048 split,
// 3 products (hi*hi -> C0; hi*lo + lo*hi -> C1; result = C0 + C1/2048).
// hi-weights (both orientations) live in LDS (XOR-chunk swizzled, conflict-free);
// lo-weights are frag-ordered in d_ws and read as coalesced dwordx4 from L2.

typedef _Float16 h8 __attribute__((ext_vector_type(8)));
typedef _Float16 h4 __attribute__((ext_vector_type(4)));
typedef float    f4 __attribute__((ext_vector_type(4)));

#define MFMA16(a,b,c) __builtin_amdgcn_mfma_f32_16x16x32_f16((a),(b),(c),0,0,0)
#define LBAR() asm volatile("s_waitcnt lgkmcnt(0)" ::: "memory")
#define DT_C 0.01f

// ---- LDS image layout (bytes); image [0,IMG_BYTES) is copied from ws ----
#define OFF_W2T 0        // [128 n][128 c] f16 hi, chunk-swizzled  (fwd z2)
#define OFF_W2  32768    // [128 c][128 n] f16 hi, swizzled        (bwd g1)
#define OFF_D2T 65536    // fwd u2
#define OFF_D2  98304    // bwd h1
#define OFF_W1T 131072   // [128 n][16 k] f16 hi, straight         (fwd z1)
#define OFF_D1T 135168   // [128 n][16 m] (cols 10..15 = 0)        (fwd u1)
#define OFF_W1R 139264   // [16 k][128 c] swizzled                 (bwd gx)
#define OFF_D1R 143360   // [16 m][128 c] (rows 10..15 = 0)        (bwd gd)
#define OFF_TB  147456   // f32 tables: b1,b2,db1,db2,w3,dWc^2 (6*128)
#define IMG_BYTES 150528
#define OFF_ACTH 150528  // [16 s][128 u] f16 hi act, chunk-swizzled
#define OFF_ACTL 154624
#define OFF_GBUF 158720  // [16 s][20] f32 (gx / gd bounce)
#define LDS_BYTES 160000
// ---- ws regions beyond the LDS image ----
#define WS_LOBIG 150528  // 4 arrays x 8rt x 4kt x 64lane x 8 f16 (lo*2048)
#define WS_Z1LO  281600  // 8ct x 64 x 8
#define WS_U1LO  289792
#define WS_GXLO  297984  // 4kt x 64 x 8
#define WS_GDLO  302080
// ws needed: 306176 bytes

__device__ __forceinline__ int swz8(int c, int r){ return (((c>>3) ^ (r&15))<<3) | (c&7); }

__device__ __forceinline__ float hiPart(float v){
  float hf = (float)(_Float16)v;
  if (fabsf(v) < 6.1035156e-5f) hf = 0.f;   // never feed f16 denormals to MFMA
  return hf;
}
__device__ __forceinline__ void splitHL(float v, _Float16 &hi, _Float16 &lo){
  float hf = hiPart(v);
  hi = (_Float16)hf;
  lo = (_Float16)((v - hf) * 2048.f);
}

// ================= prep kernel: build LDS image + lo-frag arrays in ws =================
__global__ void cm_prep(const float* __restrict__ wW1, const float* __restrict__ wb1,
                        const float* __restrict__ wW2, const float* __restrict__ wb2,
                        const float* __restrict__ wW3,
                        const float* __restrict__ dW1, const float* __restrict__ db1,
                        const float* __restrict__ dW2, const float* __restrict__ db2,
                        const float* __restrict__ dWc,
                        unsigned char* __restrict__ ws)
{
  const int tid = blockIdx.x * blockDim.x + threadIdx.x;
  const int nth = gridDim.x * blockDim.x;

  // 1. big hi arrays (swizzled row-major images). arr: 0=W2T 1=W2 2=D2T 3=D2
  _Float16* img = (_Float16*)ws;
  for (int i = tid; i < 65536; i += nth){
    int arr = i >> 14, e = i & 16383, r = e >> 7, c = e & 127;
    const float* src = (arr < 2) ? wW2 : dW2;
    float v = (arr & 1) ? src[r*128 + c] : src[c*128 + r];
    img[arr*16384 + r*128 + swz8(c, r)] = (_Float16)hiPart(v);
  }
  // 2. W1T [128 n][16 k]
  { _Float16* p = (_Float16*)(ws + OFF_W1T);
    for (int i = tid; i < 2048; i += nth){ int n = i>>4, k = i&15; p[n*16+k] = (_Float16)hiPart(wW1[k*128+n]); } }
  // 3. D1T [128 n][16 m], cols >=10 zero
  { _Float16* p = (_Float16*)(ws + OFF_D1T);
    for (int i = tid; i < 2048; i += nth){ int n = i>>4, m = i&15;
      float v = (m<10) ? dW1[m*128+n] : 0.f; p[n*16+m] = (_Float16)hiPart(v); } }
  // 4. W1R [16 k][128 c] swizzled
  { _Float16* p = (_Float16*)(ws + OFF_W1R);
    for (int i = tid; i < 2048; i += nth){ int k = i>>7, c = i&127;
      p[k*128 + swz8(c,k)] = (_Float16)hiPart(wW1[k*128+c]); } }
  // 5. D1R [16 m][128 c] swizzled, rows >=10 zero
  { _Float16* p = (_Float16*)(ws + OFF_D1R);
    for (int i = tid; i < 2048; i += nth){ int m = i>>7, c = i&127;
      float v = (m<10) ? dW1[m*128+c] : 0.f; p[m*128 + swz8(c,m)] = (_Float16)hiPart(v); } }
  // 6. f32 tables (C-layout == identity)
  { float* tb = (float*)(ws + OFF_TB);
    for (int i = tid; i < 128; i += nth){
      tb[i] = wb1[i]; tb[128+i] = wb2[i]; tb[256+i] = db1[i]; tb[384+i] = db2[i];
      tb[512+i] = wW3[i]; float w = dWc[i]; tb[640+i] = w*w; } }
  // 7. big lo frag arrays (lo*2048), frag-linear: ((arr*8+rt)*4+kt)*64+lane)*8+j
  { _Float16* lob = (_Float16*)(ws + WS_LOBIG);
    for (int i = tid; i < 65536; i += nth){
      int j = i&7, lane = (i>>3)&63, kt = (i>>9)&3, rt = (i>>11)&7, arr = i>>14;
      int row = rt*16 + (lane&15), col = kt*32 + (lane>>4)*8 + j;
      const float* src = (arr < 2) ? wW2 : dW2;
      float v = (arr & 1) ? src[row*128 + col] : src[col*128 + row];
      float hf = hiPart(v);
      lob[i] = (_Float16)((v - hf)*2048.f);
    } }
  // 8. z1 lo frags (from W1T orientation, k>=16 zero)
  { _Float16* p = (_Float16*)(ws + WS_Z1LO);
    for (int i = tid; i < 4096; i += nth){
      int j = i&7, lane = (i>>3)&63, ct = i>>9;
      int row = ct*16 + (lane&15), k = (lane>>4)*8 + j;
      float v = (k < 16) ? wW1[k*128 + row] : 0.f;
      float hf = hiPart(v); p[i] = (_Float16)((v-hf)*2048.f); } }
  // 9. u1 lo frags (from D1T orientation, m>=10 zero)
  { _Float16* p = (_Float16*)(ws + WS_U1LO);
    for (int i = tid; i < 4096; i += nth){
      int j = i&7, lane = (i>>3)&63, ct = i>>9;
      int row = ct*16 + (lane&15), m = (lane>>4)*8 + j;
      float v = (m < 10) ? dW1[m*128 + row] : 0.f;
      float hf = hiPart(v); p[i] = (_Float16)((v-hf)*2048.f); } }
  // 10. gx lo frags (W1R orientation)
  { _Float16* p = (_Float16*)(ws + WS_GXLO);
    for (int i = tid; i < 2048; i += nth){
      int j = i&7, lane = (i>>3)&63, kt = i>>9;
      int rk = lane&15, col = kt*32 + (lane>>4)*8 + j;
      float v = wW1[rk*128 + col];
      float hf = hiPart(v); p[i] = (_Float16)((v-hf)*2048.f); } }
  // 11. gd lo frags (D1R orientation, rows >=10 zero)
  { _Float16* p = (_Float16*)(ws + WS_GDLO);
    for (int i = tid; i < 2048; i += nth){
      int j = i&7, lane = (i>>3)&63, kt = i>>9;
      int rm = lane&15, col = kt*32 + (lane>>4)*8 + j;
      float v = (rm < 10) ? dW1[rm*128 + col] : 0.f;
      float hf = hiPart(v); p[i] = (_Float16)((v-hf)*2048.f); } }
}

// ================= main-kernel helpers =================
__device__ __forceinline__ void loadAct(const _Float16* actH, const _Float16* actL,
                                        h8 (&aH)[4], h8 (&aL)[4], int ln15, int g){
#pragma unroll
  for (int kt = 0; kt < 4; ++kt){
    int idx = ln15*128 + ((((kt*4+g) ^ ln15)) << 3);
    aH[kt] = *(const h8*)&actH[idx];
    aL[kt] = *(const h8*)&actL[idx];
  }
}

__device__ __forceinline__ void packTile(f4 v, int ct, _Float16* actH, _Float16* actL, int ln15, int g){
  h4 hh, ll;
#pragma unroll
  for (int r = 0; r < 4; ++r){ _Float16 a, b; splitHL(v[r], a, b); hh[r] = a; ll[r] = b; }
  int idx = ln15*128 + ((((ct*2 + (g>>1)) ^ ln15)) << 3) + ((g&1) << 2);
  *(h4*)&actH[idx] = hh;
  *(h4*)&actL[idx] = ll;
}

__device__ __forceinline__ void bigLayer(const _Float16* Whi, const h8* Wlo, const float* bias,
                                         const h8 (&aH)[4], const h8 (&aL)[4], f4 (&cc)[8],
                                         int ln15, int g, int lane){
#pragma unroll
  for (int ct = 0; ct < 8; ++ct){
    f4 c0;
    if (bias) c0 = *(const f4*)&bias[ct*16 + g*4];
    else      c0 = (f4){0.f,0.f,0.f,0.f};
    f4 c1 = {0.f,0.f,0.f,0.f};
#pragma unroll
    for (int kt = 0; kt < 4; ++kt){
      h8 wh = *(const h8*)&Whi[(ct*16 + ln15)*128 + ((((kt*4+g) ^ ln15)) << 3)];
      h8 wl = Wlo[(ct*4 + kt)*64 + lane];
      c0 = MFMA16(wh, aH[kt], c0);
      c1 = MFMA16(wh, aL[kt], c1);
      c1 = MFMA16(wl, aH[kt], c1);
    }
    cc[ct] = c0 + c1 * (1.f/2048.f);
  }
}

__device__ __forceinline__ void smallLayer(const _Float16* Whi, const h8* Wlo, const float* bias,
                                           h8 bH, h8 bL, f4 (&cc)[8], int ln15, int g, int lane){
#pragma unroll
  for (int ct = 0; ct < 8; ++ct){
    f4 c0 = *(const f4*)&bias[ct*16 + g*4];
    f4 c1 = {0.f,0.f,0.f,0.f};
    h8 wh = *(const h8*)&Whi[(ct*16 + ln15)*16 + ((g&1) << 3)];
    h8 wl = Wlo[ct*64 + lane];
    c0 = MFMA16(wh, bH, c0);
    c1 = MFMA16(wh, bL, c1);
    c1 = MFMA16(wl, bH, c1);
    cc[ct] = c0 + c1 * (1.f/2048.f);
  }
}

__device__ __forceinline__ f4 gradLayer16(const _Float16* Whi, const h8* Wlo,
                                          const h8 (&aH)[4], const h8 (&aL)[4],
                                          int ln15, int g, int lane){
  f4 c0 = {0.f,0.f,0.f,0.f}, c1 = {0.f,0.f,0.f,0.f};
#pragma unroll
  for (int kt = 0; kt < 4; ++kt){
    h8 wh = *(const h8*)&Whi[ln15*128 + ((((kt*4+g) ^ ln15)) << 3)];
    h8 wl = Wlo[kt*64 + lane];
    c0 = MFMA16(wh, aH[kt], c0);
    c1 = MFMA16(wh, aL[kt], c1);
    c1 = MFMA16(wl, aH[kt], c1);
  }
  return c0 + c1 * (1.f/2048.f);
}

// ================= main kernel =================
__global__ __launch_bounds__(64, 1) void cm_mfma(const float* __restrict__ eps,
                                                 const unsigned char* __restrict__ ws,
                                                 float* __restrict__ out)
{
  __shared__ __align__(16) unsigned char LDS[LDS_BYTES];
  const int lane = threadIdx.x;
  const int ln15 = lane & 15, g = lane >> 4;

  // stage the precomputed LDS image (single wave, plain copy)
  {
    const f4* src = (const f4*)ws;
    f4* dst = (f4*)LDS;
    for (int i = lane; i < IMG_BYTES/16; i += 64) dst[i] = src[i];
  }
  asm volatile("s_waitcnt vmcnt(0) lgkmcnt(0)" ::: "memory");

  const _Float16* W2T = (const _Float16*)(LDS + OFF_W2T);
  const _Float16* W2R = (const _Float16*)(LDS + OFF_W2);
  const _Float16* D2T = (const _Float16*)(LDS + OFF_D2T);
  const _Float16* D2R = (const _Float16*)(LDS + OFF_D2);
  const _Float16* W1T = (const _Float16*)(LDS + OFF_W1T);
  const _Float16* D1T = (const _Float16*)(LDS + OFF_D1T);
  const _Float16* W1R = (const _Float16*)(LDS + OFF_W1R);
  const _Float16* D1R = (const _Float16*)(LDS + OFF_D1R);
  const float*    tb  = (const float*)(LDS + OFF_TB);
  _Float16* actH = (_Float16*)(LDS + OFF_ACTH);
  _Float16* actL = (_Float16*)(LDS + OFF_ACTL);
  float*    gbuf = (float*)(LDS + OFF_GBUF);

  const h8* loW2T = (const h8*)(ws + WS_LOBIG);
  const h8* loW2R = (const h8*)(ws + WS_LOBIG + 32768);
  const h8* loD2T = (const h8*)(ws + WS_LOBIG + 65536);
  const h8* loD2R = (const h8*)(ws + WS_LOBIG + 98304);
  const h8* loZ1  = (const h8*)(ws + WS_Z1LO);
  const h8* loU1  = (const h8*)(ws + WS_U1LO);
  const h8* loGX  = (const h8*)(ws + WS_GXLO);
  const h8* loGD  = (const h8*)(ws + WS_GDLO);

  const int b0 = blockIdx.x * 16;
  const float* ep = eps + (size_t)(b0 + ln15) * 384;
  float*       op = out + (size_t)(b0 + ln15) * 384;

  float xiS[8];
#pragma unroll
  for (int j = 0; j < 8; ++j) xiS[j] = 0.f;

  // eps for t=0 (g0 lanes own samples' strain)
  float e0=0,e1=0,e2=0,e3=0,e4=0,e5=0;
  if (g == 0){
    float2 a = *(const float2*)(ep);     e0=a.x; e1=a.y;
    float2 b = *(const float2*)(ep + 2); e2=b.x; e3=b.y;
    float2 c = *(const float2*)(ep + 4); e4=c.x; e5=c.y;
  }

  for (int t = 0; t < 64; ++t){
    // ---- build x0 A-frag: x0 = [e-eye (6), xi (10)], K padded to 32 ----
    float xv[8];
    if (g == 0){
      xv[0]=e0-1.f; xv[1]=e1; xv[2]=e2; xv[3]=e3-1.f; xv[4]=e4; xv[5]=e5-1.f;
      xv[6]=xiS[0]; xv[7]=xiS[1];
    } else if (g == 1){
#pragma unroll
      for (int j = 0; j < 8; ++j) xv[j] = xiS[j];       // xi[2..9]
    } else {
#pragma unroll
      for (int j = 0; j < 8; ++j) xv[j] = 0.f;
    }
    h8 xHi, xLo;
#pragma unroll
    for (int j = 0; j < 8; ++j){ _Float16 a, b; splitHL(xv[j], a, b); xHi[j]=a; xLo[j]=b; }

    // prefetch next step's eps (latency hidden under this step's compute)
    float n0=e0,n1=e1,n2=e2,n3=e3,n4=e4,n5=e5;
    if (g == 0 && t < 63){
      const float* p = ep + (t+1)*6;
      float2 a = *(const float2*)(p);     n0=a.x; n1=a.y;
      float2 b = *(const float2*)(p + 2); n2=b.x; n3=b.y;
      float2 c = *(const float2*)(p + 4); n4=c.x; n5=c.y;
    }

    f4 cc[8], r1v[8], p1v[8];
    h8 aH[4], aL[4];

    // ---- z1 = x0@W1 + b1 ; a1 = relu(z1)^2 ----
    smallLayer(W1T, loZ1, tb + 0, xHi, xLo, cc, ln15, g, lane);
#pragma unroll
    for (int ct = 0; ct < 8; ++ct){
      f4 r, a;
#pragma unroll
      for (int q = 0; q < 4; ++q){ float rr = fmaxf(cc[ct][q], 0.f); r[q] = rr; a[q] = rr*rr; }
      r1v[ct] = r;
      packTile(a, ct, actH, actL, ln15, g);
    }
    LBAR();

    // ---- z2 = a1@W2 + b2 ; gz2 = 2*relu(z2)*W3 ----
    loadAct(actH, actL, aH, aL, ln15, g);
    bigLayer(W2T, loW2T, tb + 128, aH, aL, cc, ln15, g, lane);
#pragma unroll
    for (int ct = 0; ct < 8; ++ct){
      f4 w3 = *(const f4*)&tb[512 + ct*16 + g*4];
      f4 gz;
#pragma unroll
      for (int q = 0; q < 4; ++q) gz[q] = 2.f * fmaxf(cc[ct][q], 0.f) * w3[q];
      packTile(gz, ct, actH, actL, ln15, g);
    }
    LBAR();

    // ---- g1[c] = sum_n W2[c][n] gz2[n] ; gz1 = 2*g1*relu(z1) ----
    loadAct(actH, actL, aH, aL, ln15, g);
    bigLayer(W2R, loW2R, nullptr, aH, aL, cc, ln15, g, lane);
#pragma unroll
    for (int ct = 0; ct < 8; ++ct){
      f4 gz;
#pragma unroll
      for (int q = 0; q < 4; ++q) gz[q] = 2.f * cc[ct][q] * r1v[ct][q];
      packTile(gz, ct, actH, actL, ln15, g);
    }
    LBAR();

    // ---- gx[k] = sum_c W1[k][c] gz1[c]  (k=0..15) ----
    loadAct(actH, actL, aH, aL, ln15, g);
    f4 gx = gradLayer16(W1R, loGX, aH, aL, ln15, g, lane);
    // stress = gx[0..5]
    if (g == 0){
      *(float2*)(op + t*6)     = make_float2(gx[0], gx[1]);
      *(float2*)(op + t*6 + 2) = make_float2(gx[2], gx[3]);
    } else if (g == 1){
      *(float2*)(op + t*6 + 4) = make_float2(gx[0], gx[1]);
    }
    *(f4*)(gbuf + ln15*20 + g*4) = gx;   // bounce k=6..15 for d
    LBAR();

    // ---- d = -gx[6..15] as A-frag (K=10, padded to 32) ----
    float dv[8];
    if (g == 0){
      float2 a = *(const float2*)(gbuf + ln15*20 + 6);
      f4     b = *(const f4*)    (gbuf + ln15*20 + 8);
      float2 c = *(const float2*)(gbuf + ln15*20 + 12);
      dv[0]=-a.x; dv[1]=-a.y; dv[2]=-b[0]; dv[3]=-b[1]; dv[4]=-b[2]; dv[5]=-b[3]; dv[6]=-c.x; dv[7]=-c.y;
    } else if (g == 1){
      float2 a = *(const float2*)(gbuf + ln15*20 + 14);
      dv[0]=-a.x; dv[1]=-a.y;
#pragma unroll
      for (int j = 2; j < 8; ++j) dv[j] = 0.f;
    } else {
#pragma unroll
      for (int j = 0; j < 8; ++j) dv[j] = 0.f;
    }
    h8 dHi, dLo;
#pragma unroll
    for (int j = 0; j < 8; ++j){ _Float16 a, b; splitHL(dv[j], a, b); dHi[j]=a; dLo[j]=b; }

    // ---- u1 = d@D1 + db1 ; q1 = relu(u1)^2 ----
    smallLayer(D1T, loU1, tb + 256, dHi, dLo, cc, ln15, g, lane);
#pragma unroll
    for (int ct = 0; ct < 8; ++ct){
      f4 r, a;
#pragma unroll
      for (int q = 0; q < 4; ++q){ float rr = fmaxf(cc[ct][q], 0.f); r[q] = rr; a[q] = rr*rr; }
      p1v[ct] = r;
      packTile(a, ct, actH, actL, ln15, g);
    }
    LBAR();

    // ---- u2 = q1@D2 + db2 ; hu2 = 2*relu(u2)*dWc^2 ----
    loadAct(actH, actL, aH, aL, ln15, g);
    bigLayer(D2T, loD2T, tb + 384, aH, aL, cc, ln15, g, lane);
#pragma unroll
    for (int ct = 0; ct < 8; ++ct){
      f4 dc = *(const f4*)&tb[640 + ct*16 + g*4];
      f4 hu;
#pragma unroll
      for (int q = 0; q < 4; ++q) hu[q] = 2.f * fmaxf(cc[ct][q], 0.f) * dc[q];
      packTile(hu, ct, actH, actL, ln15, g);
    }
    LBAR();

    // ---- h1[c] = sum_n D2[c][n] hu2[n] ; hu1 = 2*h1*relu(u1) ----
    loadAct(actH, actL, aH, aL, ln15, g);
    bigLayer(D2R, loD2R, nullptr, aH, aL, cc, ln15, g, lane);
#pragma unroll
    for (int ct = 0; ct < 8; ++ct){
      f4 hu;
#pragma unroll
      for (int q = 0; q < 4; ++q) hu[q] = 2.f * cc[ct][q] * p1v[ct][q];
      packTile(hu, ct, actH, actL, ln15, g);
    }
    LBAR();

    // ---- gd[m] = sum_c D1[m][c] hu1[c] ; xi += DT*gd ----
    loadAct(actH, actL, aH, aL, ln15, g);
    f4 gd = gradLayer16(D1R, loGD, aH, aL, ln15, g, lane);
    *(f4*)(gbuf + ln15*20 + g*4) = gd;
    LBAR();

    if (g == 0){
      float2 a = *(const float2*)(gbuf + ln15*20);
      xiS[0] += DT_C * a.x; xiS[1] += DT_C * a.y;
    } else if (g == 1){
      float2 a = *(const float2*)(gbuf + ln15*20 + 2);
      f4     b = *(const f4*)    (gbuf + ln15*20 + 4);
      float2 c = *(const float2*)(gbuf + ln15*20 + 8);
      xiS[0] += DT_C * a.x; xiS[1] += DT_C * a.y;
      xiS[2] += DT_C * b[0]; xiS[3] += DT_C * b[1]; xiS[4] += DT_C * b[2]; xiS[5] += DT_C * b[3];
      xiS[6] += DT_C * c.x; xiS[7] += DT_C * c.y;
    }

    e0=n0; e1=n1; e2=n2; e3=n3; e4=n4; e5=n5;
  }
}

extern "C" void kernel_launch(void* const* d_in, const int* in_sizes, int n_in,
                              void* d_out, int out_size, void* d_ws, size_t ws_size,
                              hipStream_t stream) {
  const float* eps = (const float*)d_in[0];
  const float* wW1 = (const float*)d_in[1];
  const float* wb1 = (const float*)d_in[2];
  const float* wW2 = (const float*)d_in[3];
  const float* wb2 = (const float*)d_in[4];
  const float* wW3 = (const float*)d_in[5];
  // d_in[6] = wb3: constant, vanishes in gradient
  const float* dW1 = (const float*)d_in[7];
  const float* db1 = (const float*)d_in[8];
  const float* dW2 = (const float*)d_in[9];
  const float* db2 = (const float*)d_in[10];
  const float* dWc = (const float*)d_in[11];
  unsigned char* ws = (unsigned char*)d_ws;
  float* out = (float*)d_out;

  cm_prep<<<dim3(256), dim3(256), 0, stream>>>(wW1, wb1, wW2, wb2, wW3,
                                               dW1, db1, dW2, db2, dWc, ws);
  cm_mfma<<<dim3(128), dim3(64), 0, stream>>>(eps, ws, out);
}